// Round 7
// baseline (487.906 us; speedup 1.0000x reference)
//
#include <hip/hip_runtime.h>

// Demosaic BG-Bayer (top-left red) -> RGB, closed-form stencil.
// Each thread computes a 2(row)x4(col) output block from 4 input rows.
// Edge values come from neighboring lanes via shuffle (wave = 64 consecutive
// strips of one row; 512 strips/row so waves never straddle rows).
//
// Round-4 post-mortem: XCD swizzle was neutral — input (134 MB) fits in the
// 256 MB L3, which is shared across XCDs, so cross-XCD re-reads never hit HBM.
// Round-5 change: NON-TEMPORAL output stores. Theory: the 403 MB write stream
// evicts input lines from L2/L3 between their 1st and 2nd use and churns L3
// with never-re-read data; nt stores keep the write stream out of the caches.

#define HH 2048
#define WW 2048

typedef float v4f __attribute__((ext_vector_type(4)));

__device__ __forceinline__ void nt_store4(float* p, float a, float b, float c, float d) {
    v4f t;
    t.x = a; t.y = b; t.z = c; t.w = d;
    __builtin_nontemporal_store(t, (v4f*)p);
}

__global__ __launch_bounds__(256) void demosaic_bg_kernel(const float* __restrict__ in,
                                                          float* __restrict__ out) {
    const int strips_per_row = WW / 4;  // 512

    // bijective XCD-aware remap (gridDim.x == 16384, divisible by 8) — kept
    // from round 4 (neutral, harmless) so this round is a pure nt-store A/B.
    int bid = (int)blockIdx.x;
    int nb = (bid & 7) * ((int)gridDim.x >> 3) + (bid >> 3);
    int gid = nb * 256 + (int)threadIdx.x;

    int s = gid & (strips_per_row - 1);
    int t = gid >> 9;
    int yp = t & (HH / 2 - 1);   // row-pair index
    int bimg = t >> 10;          // batch
    int y = yp << 1;             // even
    int x0 = s << 2;
    int lane = (int)threadIdx.x & 63;

    const float* __restrict__ img = in + (size_t)bimg * HH * WW;

    const int i0 = (y == 0) ? 1 : y - 1;
    const int i3 = (y + 2 > HH - 2) ? (HH - 2) : y + 2;

    const float* pa = img + (size_t)i0 * WW;
    const float* pb = img + (size_t)y * WW;
    const float* pc = img + (size_t)(y + 1) * WW;
    const float* pd = img + (size_t)i3 * WW;

    float4 a = *(const float4*)(pa + x0);
    float4 b = *(const float4*)(pb + x0);
    float4 c = *(const float4*)(pc + x0);
    float4 d = *(const float4*)(pd + x0);

    // in-wave edge exchange (only la, lb, lc and rb, rc, rd are consumed)
    float la = __shfl_up(a.w, 1);
    float lb = __shfl_up(b.w, 1);
    float lc = __shfl_up(c.w, 1);
    float rb = __shfl_down(b.x, 1);
    float rc = __shfl_down(c.x, 1);
    float rd = __shfl_down(d.x, 1);

    if (lane == 0) {
        if (x0 == 0) {           // clamp: p[-1] -> p[1]
            la = a.y; lb = b.y; lc = c.y;
        } else {                 // strip boundary between waves: real load
            la = pa[x0 - 1]; lb = pb[x0 - 1]; lc = pc[x0 - 1];
        }
    }
    if (lane == 63) {
        if (x0 + 4 > WW - 2) {   // clamp: p[2048] -> p[2046] (x0 == 2044)
            rb = b.z; rc = c.z; rd = d.z;
        } else {
            rb = pb[x0 + 4]; rc = pc[x0 + 4]; rd = pd[x0 + 4];
        }
    }

    // ---- even output row y: [red, green, red, green] ----
    float Rex = b.x;
    float Gex = 0.25f * (a.x + c.x + lb + b.y);
    float Bex = 0.25f * (la + a.y + lc + c.y);

    float Rey = 0.5f * (b.x + b.z);
    float Gey = b.y;
    float Bey = 0.5f * (a.y + c.y);

    float Rez = b.z;
    float Gez = 0.25f * (a.z + c.z + b.y + b.w);
    float Bez = 0.25f * (a.y + a.w + c.y + c.w);

    float Rew = 0.5f * (b.z + rb);
    float Gew = b.w;
    float Bew = 0.5f * (a.w + c.w);

    // ---- odd output row y+1: [green, blue, green, blue] ----
    float Rox = 0.5f * (b.x + d.x);
    float Gox = c.x;
    float Box = 0.5f * (lc + c.y);

    float Roy = 0.25f * (b.x + b.z + d.x + d.z);
    float Goy = 0.25f * (b.y + d.y + c.x + c.z);
    float Boy = c.y;

    float Roz = 0.5f * (b.z + d.z);
    float Goz = c.z;
    float Boz = 0.5f * (c.y + c.w);

    float Row = 0.25f * (b.z + rb + d.z + rd);
    float Gow = 0.25f * (b.w + d.w + c.z + rc);
    float Bow = c.w;

    const size_t plane = (size_t)HH * WW;
    size_t obase = (size_t)bimg * 3 * plane + (size_t)y * WW + x0;
    nt_store4(out + obase,                  Rex, Rey, Rez, Rew);
    nt_store4(out + obase + WW,             Rox, Roy, Roz, Row);
    nt_store4(out + obase + plane,          Gex, Gey, Gez, Gew);
    nt_store4(out + obase + plane + WW,     Gox, Goy, Goz, Gow);
    nt_store4(out + obase + 2 * plane,      Bex, Bey, Bez, Bew);
    nt_store4(out + obase + 2 * plane + WW, Box, Boy, Boz, Bow);
}

extern "C" void kernel_launch(void* const* d_in, const int* in_sizes, int n_in,
                              void* d_out, int out_size, void* d_ws, size_t ws_size,
                              hipStream_t stream) {
    const float* in = (const float*)d_in[0];
    float* out = (float*)d_out;
    const int threads = 8 * (HH / 2) * (WW / 4);   // 4.19M
    dim3 block(256);
    dim3 grid(threads / 256);                      // 16384
    demosaic_bg_kernel<<<grid, block, 0, stream>>>(in, out);
}